// Round 11
// baseline (77.089 us; speedup 1.0000x reference)
//
#include <hip/hip_runtime.h>
#include <hip/hip_bf16.h>
#include <stdint.h>

typedef __attribute__((ext_vector_type(8))) short bf16x8;
typedef __attribute__((ext_vector_type(4))) float f32x4;
typedef __attribute__((ext_vector_type(16))) float f32x16;
typedef __attribute__((ext_vector_type(2))) unsigned int uint32x2;
typedef __attribute__((address_space(3))) void lds_t;
typedef __attribute__((address_space(1))) void glb_t;

#define B_ 4
#define S_ 2048
#define E_ 1024
#define M_ (B_*S_)
#define QTS 152   // qt row stride: 304 B = 12 banks -> 2-way (free) on b128 reads
#define PPB 2     // positions per block (dual-stream)

static __device__ __forceinline__ ushort f2bf(float f) {
  uint32_t u = __float_as_uint(f);
  u += 0x7fffu + ((u >> 16) & 1u);
  return (ushort)(u >> 16);
}

static __device__ __forceinline__ uint32_t pk_bf16(float lo, float hi) {
  uint32_t r;
  asm("v_cvt_pk_bf16_f32 %0, %1, %2" : "=v"(r) : "v"(lo), "v"(hi));
  return r;
}
static __device__ __forceinline__ float fexp2(float x) {
  float r;
  asm("v_exp_f32 %0, %1" : "=v"(r) : "v"(x));
  return r;
}

// X = [a_lo | b_lo], Y = [a_hi | b_hi]  (lane halves), convention-proof.
static __device__ __forceinline__ void half_zip(uint32_t a, uint32_t b, bool convA,
                                                uint32_t& X, uint32_t& Y) {
  if (convA) {
    uint32x2 r = __builtin_amdgcn_permlane32_swap(b, a, false, false);
    Y = r[0]; X = r[1];
  } else {
    uint32x2 r = __builtin_amdgcn_permlane32_swap(a, b, false, false);
    X = r[0]; Y = r[1];
  }
}

// ---------------- Stage 1: quantum head-attention via MFMA ----------------
// R10 dual-stream structure with __launch_bounds__(256) RESTORED (empirical
// invariant: every green kernel in this lineage carries exactly this
// attribute; all three reds changed it). Wave w = head-quadrant hi=w for both
// positions. Gen issues both x-loads back-to-back, one barrier, then the two
// position-chains are manually zipped stage-by-stage (S-MFMA0/1, ds0/1,
// exp0/1, pack0+PV0 / pack1+PV1) with separate f32x16 accumulators; rowsum
// free at reg4 via ones rows 8 & 12.
__global__ __launch_bounds__(256) void qattn(const float* __restrict__ x,
                                             const float* __restrict__ theta,
                                             ushort* __restrict__ outr) {
  const int wave = threadIdx.x >> 6;
  const int lane = threadIdx.x & 63;
  const int l31 = lane & 31, hw = lane >> 5;

  // XCD-aware swizzle (4096 = 8 x 512, bijective)
  const int bid = blockIdx.x;
  const int pair = (bid & 7) * 512 + (bid >> 3);
  const int bs0 = pair * PPB, bs1 = bs0 + 1;

  __shared__ __align__(16) ushort qL[PPB][129 * 8];    // scaled q, row 128 = zeros (K-pad)
  __shared__ __align__(16) ushort qT[PPB][16 * QTS];   // raw q^T, rows 8 & 12 = ones

  // permlane32_swap convention probe (wave-uniform)
  uint32x2 pr = __builtin_amdgcn_permlane32_swap((uint32_t)lane, (uint32_t)(lane + 1000),
                                                 false, false);
  const bool convA = (__builtin_amdgcn_readfirstlane((int)pr[0]) >= 1000);

  // ---- generation (R9-green math; loads hoisted so both overlap) ----
  const int gh  = 32 * wave + (lane >> 1);
  const int gdh = (lane & 1) * 4;
  const float4 xv0 = *(const float4*)(x + (size_t)bs0 * E_ + gh * 8 + gdh);
  const float4 xv1 = *(const float4*)(x + (size_t)bs1 * E_ + gh * 8 + gdh);

  auto genStore = [&](const float4& xv, int sel) {
    ushort* qpg = qL[sel];
    ushort* qtg = qT[sel];
    float q[4];
    q[0] = __cosf(xv.x + theta[gdh + 0]);
    q[1] = __cosf(xv.y + theta[gdh + 1]);
    q[2] = __cosf(xv.z + theta[gdh + 2]);
    q[3] = __cosf(xv.w + theta[gdh + 3]);

    // QS^2 = (1/sqrt(8)) * log2(e): folds softmax scale + exp->exp2 into QK operands
    const float QS = 0.71419165f;
    uint2 pw;
    pw.x = pk_bf16(q[0] * QS, q[1] * QS);
    pw.y = pk_bf16(q[2] * QS, q[3] * QS);
    *(uint2*)(qpg + gh * 8 + gdh) = pw;                    // scaled, for QK^T operands

    #pragma unroll
    for (int j = 0; j < 4; ++j)                            // raw, for PV A-operand
      qtg[(gdh + j) * QTS + gh] = f2bf(q[j]);
    #pragma unroll
    for (int j = 0; j < 4; ++j)                            // rows 8..15: ones at 8,12
      qtg[(8 + gdh + j) * QTS + gh] = (j == 0) ? (ushort)0x3F80u : (ushort)0u;

    if (lane == 0) *(uint4*)(qpg + 128 * 8) = make_uint4(0, 0, 0, 0);  // K-pad row
  };
  genStore(xv0, 0);
  genStore(xv1, 1);
  __syncthreads();
  __builtin_amdgcn_sched_barrier(0);

  const int hi = wave;
  const bf16x8 zf = {};
  const ushort* qp0 = qL[0];
  const ushort* qt0 = qT[0];
  const ushort* qp1 = qL[1];
  const ushort* qt1 = qT[1];

  // prefetch both streams' A-row frags + B frags (independent ds_reads)
  bf16x8 aqv0[4], aqv1[4];
  #pragma unroll
  for (int gj = 0; gj < 4; ++gj) {
    const int arow = (lane < 32) ? (gj * 32 + l31) : 128;
    aqv0[gj] = *(const bf16x8*)(qp0 + arow * 8);
    aqv1[gj] = *(const bf16x8*)(qp1 + arow * 8);
  }
  const int brow = (lane < 32) ? (hi * 32 + l31) : 128;
  const bf16x8 bq0 = *(const bf16x8*)(qp0 + brow * 8);
  const bf16x8 bq1 = *(const bf16x8*)(qp1 + brow * 8);

  f32x16 oacc0 = {}, oacc1 = {};   // O^T: col h = hi*32+l31, row d=(reg&3)+8*(reg>>2)+4*hw

  #pragma unroll
  for (int gj = 0; gj < 4; ++gj) {
    // stage 1: both S-MFMAs (independent)
    f32x16 sc0 = {}, sc1 = {};
    sc0 = __builtin_amdgcn_mfma_f32_32x32x16_bf16(aqv0[gj], bq0, sc0, 0, 0, 0);
    sc1 = __builtin_amdgcn_mfma_f32_32x32x16_bf16(aqv1[gj], bq1, sc1, 0, 0, 0);
    // stage 2: PV A-frags for this gj, both streams (latency hides under exp)
    bf16x8 fA0 = *(const bf16x8*)(qt0 + (l31 & 15) * QTS + (gj * 2 + 0) * 16 + hw * 8);
    bf16x8 fB0 = *(const bf16x8*)(qt0 + (l31 & 15) * QTS + (gj * 2 + 1) * 16 + hw * 8);
    bf16x8 fA1 = *(const bf16x8*)(qt1 + (l31 & 15) * QTS + (gj * 2 + 0) * 16 + hw * 8);
    bf16x8 fB1 = *(const bf16x8*)(qt1 + (l31 & 15) * QTS + (gj * 2 + 1) * 16 + hw * 8);
    fA0 = (l31 < 16) ? fA0 : zf;  fB0 = (l31 < 16) ? fB0 : zf;
    fA1 = (l31 < 16) ? fA1 : zf;  fB1 = (l31 < 16) ? fB1 : zf;
    // stage 3: exp, both streams
    float pv0[16], pv1[16];
    #pragma unroll
    for (int k = 0; k < 16; ++k) pv0[k] = fexp2(sc0[k]);
    #pragma unroll
    for (int k = 0; k < 16; ++k) pv1[k] = fexp2(sc1[k]);
    // stage 4: pack + PV-MFMA, alternating streams per sl
    #pragma unroll
    for (int sl = 0; sl < 2; ++sl) {
      const int pb = sl * 8;
      {
        const uint32_t u = pk_bf16(pv0[pb+0], pv0[pb+1]);
        const uint32_t v = pk_bf16(pv0[pb+2], pv0[pb+3]);
        const uint32_t w = pk_bf16(pv0[pb+4], pv0[pb+5]);
        const uint32_t z = pk_bf16(pv0[pb+6], pv0[pb+7]);
        uint32_t f0, f1, f2, f3;
        half_zip(u, w, convA, f0, f2);
        half_zip(v, z, convA, f1, f3);
        uint32_t fr[4] = {f0, f1, f2, f3};
        oacc0 = __builtin_amdgcn_mfma_f32_32x32x16_bf16((sl == 0) ? fA0 : fB0,
                                                        *(const bf16x8*)fr, oacc0, 0, 0, 0);
      }
      {
        const uint32_t u = pk_bf16(pv1[pb+0], pv1[pb+1]);
        const uint32_t v = pk_bf16(pv1[pb+2], pv1[pb+3]);
        const uint32_t w = pk_bf16(pv1[pb+4], pv1[pb+5]);
        const uint32_t z = pk_bf16(pv1[pb+6], pv1[pb+7]);
        uint32_t f0, f1, f2, f3;
        half_zip(u, w, convA, f0, f2);
        half_zip(v, z, convA, f1, f3);
        uint32_t fr[4] = {f0, f1, f2, f3};
        oacc1 = __builtin_amdgcn_mfma_f32_32x32x16_bf16((sl == 0) ? fA1 : fB1,
                                                        *(const bf16x8*)fr, oacc1, 0, 0, 0);
      }
    }
  }

  // epilogue: regs0-3 = d 0-3 (hw=0) / d 4-7 (hw=1); reg4 = rowsum (both halves)
  const int h = hi * 32 + l31;
  {
    const int s = bs0 & 2047, b = bs0 >> 11;
    const int scol = s & 127, srow = s >> 7;
    const float inv = __builtin_amdgcn_rcpf(oacc0[4]);
    const uint32_t o01 = pk_bf16(oacc0[0] * inv, oacc0[1] * inv);
    const uint32_t o23 = pk_bf16(oacc0[2] * inv, oacc0[3] * inv);
    const size_t row = (size_t)(b * 2048 + h * 16 + srow);
    *(uint2*)(outr + row * E_ + scol * 8 + hw * 4) = make_uint2(o01, o23);
  }
  {
    const int s = bs1 & 2047, b = bs1 >> 11;
    const int scol = s & 127, srow = s >> 7;
    const float inv = __builtin_amdgcn_rcpf(oacc1[4]);
    const uint32_t o01 = pk_bf16(oacc1[0] * inv, oacc1[1] * inv);
    const uint32_t o23 = pk_bf16(oacc1[2] * inv, oacc1[3] * inv);
    const size_t row = (size_t)(b * 2048 + h * 16 + srow);
    *(uint2*)(outr + row * E_ + scol * 8 + hw * 4) = make_uint2(o01, o23);
  }
}

// ---------------- W (f32) -> bf16 ----------------
__global__ __launch_bounds__(256) void wconv(const float* __restrict__ W,
                                             ushort* __restrict__ Wb) {
  const int i = blockIdx.x * 256 + threadIdx.x;
  const float4 v = ((const float4*)W)[i];
  ushort4 o;
  o.x = f2bf(v.x); o.y = f2bf(v.y); o.z = f2bf(v.z); o.w = f2bf(v.w);
  ((ushort4*)Wb)[i] = o;
}

// ---------------- Stage 2: C[m,n] = sum_k A[m,k]*W[n,k] + bias[n] ----------------
__global__ __launch_bounds__(256) void gemm_bt(const ushort* __restrict__ A,
                                               const ushort* __restrict__ Bw,
                                               const float* __restrict__ bias,
                                               float* __restrict__ C) {
  __shared__ __align__(16) ushort As[128 * 32];
  __shared__ __align__(16) ushort Bs[128 * 32];

  const int t = threadIdx.x;
  const int lane = t & 63;
  const int wavei = t >> 6;
  const int wr = wavei >> 1, wc = wavei & 1;
  const int lhi = lane >> 4, llo = lane & 15;
  const size_t ar0 = (size_t)blockIdx.x * 128;
  const size_t br0 = (size_t)blockIdx.y * 128;

  const int c0 = t, c1 = t + 256;
  const int r0 = c0 >> 2, kp0 = (c0 & 3) * 8;
  const int r1 = c1 >> 2, kp1 = (c1 & 3) * 8;

  f32x4 acc[4][4] = {};

  for (int k0 = 0; k0 < E_; k0 += 32) {
    __builtin_amdgcn_global_load_lds((const glb_t*)(A  + (ar0 + r0) * E_ + k0 + kp0),
                                     (lds_t*)(As + c0 * 8), 16, 0, 0);
    __builtin_amdgcn_global_load_lds((const glb_t*)(A  + (ar0 + r1) * E_ + k0 + kp1),
                                     (lds_t*)(As + c1 * 8), 16, 0, 0);
    __builtin_amdgcn_global_load_lds((const glb_t*)(Bw + (br0 + r0) * E_ + k0 + kp0),
                                     (lds_t*)(Bs + c0 * 8), 16, 0, 0);
    __builtin_amdgcn_global_load_lds((const glb_t*)(Bw + (br0 + r1) * E_ + k0 + kp1),
                                     (lds_t*)(Bs + c1 * 8), 16, 0, 0);
    __syncthreads();

    bf16x8 af[4], bfr[4];
    #pragma unroll
    for (int i = 0; i < 4; ++i)
      af[i] = *(const bf16x8*)(As + (wr * 64 + i * 16 + llo) * 32 + lhi * 8);
    #pragma unroll
    for (int j = 0; j < 4; ++j)
      bfr[j] = *(const bf16x8*)(Bs + (wc * 64 + j * 16 + llo) * 32 + lhi * 8);

    #pragma unroll
    for (int i = 0; i < 4; ++i)
      #pragma unroll
      for (int j = 0; j < 4; ++j)
        acc[i][j] = __builtin_amdgcn_mfma_f32_16x16x32_bf16(af[i], bfr[j], acc[i][j], 0, 0, 0);

    __syncthreads();
  }

  #pragma unroll
  for (int j = 0; j < 4; ++j) {
    const int n = (int)br0 + wc * 64 + j * 16 + llo;
    const float bj = bias[n];
    #pragma unroll
    for (int i = 0; i < 4; ++i) {
      const int mb = (int)ar0 + wr * 64 + i * 16 + lhi * 4;
      #pragma unroll
      for (int r = 0; r < 4; ++r) {
        C[(size_t)(mb + r) * E_ + n] = acc[i][j][r] + bj;
      }
    }
  }
}

extern "C" void kernel_launch(void* const* d_in, const int* in_sizes, int n_in,
                              void* d_out, int out_size, void* d_ws, size_t ws_size,
                              hipStream_t stream) {
  const float* x     = (const float*)d_in[0];
  const float* theta = (const float*)d_in[1];
  const float* W     = (const float*)d_in[2];
  const float* bias  = (const float*)d_in[3];
  float* out = (float*)d_out;

  ushort* outr = (ushort*)d_ws;
  ushort* Wb   = (ushort*)((char*)d_ws + (size_t)M_ * E_ * 2);

  qattn<<<M_ / PPB, 256, 0, stream>>>(x, theta, outr);
  wconv<<<(E_ * E_) / (256 * 4), 256, 0, stream>>>(W, Wb);
  dim3 g(M_ / 128, E_ / 128);
  gemm_bt<<<g, 256, 0, stream>>>(outr, Wb, bias, out);
}

// Round 12
// 69.666 us; speedup vs baseline: 1.1066x; 1.1066x over previous
//
#include <hip/hip_runtime.h>
#include <hip/hip_bf16.h>
#include <stdint.h>

typedef __attribute__((ext_vector_type(8))) short bf16x8;
typedef __attribute__((ext_vector_type(4))) float f32x4;
typedef __attribute__((ext_vector_type(16))) float f32x16;
typedef __attribute__((ext_vector_type(2))) unsigned int uint32x2;
typedef __attribute__((address_space(3))) void lds_t;
typedef __attribute__((address_space(1))) void glb_t;

#define B_ 4
#define S_ 2048
#define E_ 1024
#define M_ (B_*S_)
#define QTS 152   // qt row stride: 304 B = 12 banks -> 2-way (free) on b128 reads
#define PPB 2     // positions per block

static __device__ __forceinline__ ushort f2bf(float f) {
  uint32_t u = __float_as_uint(f);
  u += 0x7fffu + ((u >> 16) & 1u);
  return (ushort)(u >> 16);
}

static __device__ __forceinline__ uint32_t pk_bf16(float lo, float hi) {
  uint32_t r;
  asm("v_cvt_pk_bf16_f32 %0, %1, %2" : "=v"(r) : "v"(lo), "v"(hi));
  return r;
}
static __device__ __forceinline__ float fexp2(float x) {
  float r;
  asm("v_exp_f32 %0, %1" : "=v"(r) : "v"(x));
  return r;
}

// X = [a_lo | b_lo], Y = [a_hi | b_hi]  (lane halves), convention-proof.
static __device__ __forceinline__ void half_zip(uint32_t a, uint32_t b, bool convA,
                                                uint32_t& X, uint32_t& Y) {
  if (convA) {
    uint32x2 r = __builtin_amdgcn_permlane32_swap(b, a, false, false);
    Y = r[0]; X = r[1];
  } else {
    uint32x2 r = __builtin_amdgcn_permlane32_swap(a, b, false, false);
    X = r[0]; Y = r[1];
  }
}

// ---------------- Stage 1: quantum head-attention via MFMA ----------------
// R9-green structure (2 positions/block, sequential consume) with verified
// instruction cuts: (1) no l31<16 select on PV A-frags (A rows 16-31 only
// feed unread C rows; same-addr reads broadcast); (2) qt rows 9-11/13-15
// left uninitialized (their C rows are unread); (3) PV accumulator split
// into two 4-deep chains (halved MFMA dependency depth), joined by one
// vector add. Wave w = head-quadrant hi=w (green invariant);
// __launch_bounds__(256) mandatory (R10/R11 A/B).
__global__ __launch_bounds__(256) void qattn(const float* __restrict__ x,
                                             const float* __restrict__ theta,
                                             ushort* __restrict__ outr) {
  const int wave = threadIdx.x >> 6;
  const int lane = threadIdx.x & 63;
  const int l31 = lane & 31, hw = lane >> 5;

  // XCD-aware swizzle (4096 = 8 x 512, bijective)
  const int bid = blockIdx.x;
  const int pair = (bid & 7) * 512 + (bid >> 3);

  __shared__ __align__(16) ushort qL[PPB][129 * 8];    // scaled q, row 128 = zeros (K-pad)
  __shared__ __align__(16) ushort qT[PPB][16 * QTS];   // raw q^T, ones at rows 8 & 12

  // permlane32_swap convention probe (wave-uniform)
  uint32x2 pr = __builtin_amdgcn_permlane32_swap((uint32_t)lane, (uint32_t)(lane + 1000),
                                                 false, false);
  const bool convA = (__builtin_amdgcn_readfirstlane((int)pr[0]) >= 1000);

  // ---- generation: wave w covers head h = 32*w + (lane>>1), d-half dh ----
  auto gen = [&](int bs_g, int sel) {
    ushort* qpg = qL[sel];
    ushort* qtg = qT[sel];
    const int h  = 32 * wave + (lane >> 1);
    const int dh = (lane & 1) * 4;
    const float4 xv = *(const float4*)(x + (size_t)bs_g * E_ + h * 8 + dh);
    float q[4];
    q[0] = __cosf(xv.x + theta[dh + 0]);
    q[1] = __cosf(xv.y + theta[dh + 1]);
    q[2] = __cosf(xv.z + theta[dh + 2]);
    q[3] = __cosf(xv.w + theta[dh + 3]);

    // QS^2 = (1/sqrt(8)) * log2(e): folds softmax scale + exp->exp2 into QK operands
    const float QS = 0.71419165f;
    uint2 pw;
    pw.x = pk_bf16(q[0] * QS, q[1] * QS);
    pw.y = pk_bf16(q[2] * QS, q[3] * QS);
    *(uint2*)(qpg + h * 8 + dh) = pw;                      // scaled, for QK^T operands

    #pragma unroll
    for (int j = 0; j < 4; ++j)                            // raw, for PV A-operand
      qtg[(dh + j) * QTS + h] = f2bf(q[j]);
    qtg[(8 + dh) * QTS + h] = (ushort)0x3F80u;             // ones row 8 (dh=0) / 12 (dh=4)

    if (lane == 0) *(uint4*)(qpg + 128 * 8) = make_uint4(0, 0, 0, 0);  // K-pad row
  };

  gen(pair * PPB + 0, 0);
  gen(pair * PPB + 1, 1);
  __syncthreads();
  __builtin_amdgcn_sched_barrier(0);

  const int hi = wave;

  #pragma unroll
  for (int pp = 0; pp < PPB; ++pp) {
    const ushort* qp = qL[pp];
    const ushort* qt = qT[pp];
    const int bs = pair * PPB + pp;
    const int b = bs >> 11, s = bs & 2047;

    // prefetch all 4 A-row frags (independent ds_reads; latencies overlap)
    bf16x8 aqv[4];
    #pragma unroll
    for (int gj = 0; gj < 4; ++gj) {
      const int arow = (lane < 32) ? (gj * 32 + l31) : 128;
      aqv[gj] = *(const bf16x8*)(qp + arow * 8);
    }
    const int brow = (lane < 32) ? (hi * 32 + l31) : 128;
    const bf16x8 bq = *(const bf16x8*)(qp + brow * 8);
    const ushort* qtb = qt + (l31 & 15) * QTS + hw * 8;    // PV A-frag base (no mask needed)

    f32x16 oaccA = {}, oaccB = {};   // two 4-deep PV chains: g 0-63 / g 64-127

    #pragma unroll
    for (int gj = 0; gj < 4; ++gj) {
      f32x16 sc = {};
      sc = __builtin_amdgcn_mfma_f32_32x32x16_bf16(aqv[gj], bq, sc, 0, 0, 0);
      // PV A-frags: rows l31&15 of qt (upper lanes broadcast-read same rows;
      // they feed only C rows 16-31, which are never read)
      const bf16x8 fA = *(const bf16x8*)(qtb + (gj * 2 + 0) * 16);
      const bf16x8 fB = *(const bf16x8*)(qtb + (gj * 2 + 1) * 16);
      float pv[16];
      #pragma unroll
      for (int k = 0; k < 16; ++k) pv[k] = fexp2(sc[k]);
      #pragma unroll
      for (int sl = 0; sl < 2; ++sl) {
        const int pb = sl * 8;
        const uint32_t u = pk_bf16(pv[pb+0], pv[pb+1]);
        const uint32_t v = pk_bf16(pv[pb+2], pv[pb+3]);
        const uint32_t w = pk_bf16(pv[pb+4], pv[pb+5]);
        const uint32_t z = pk_bf16(pv[pb+6], pv[pb+7]);
        uint32_t f0, f1, f2, f3;
        half_zip(u, w, convA, f0, f2);
        half_zip(v, z, convA, f1, f3);
        uint32_t fr[4] = {f0, f1, f2, f3};
        if (gj < 2)
          oaccA = __builtin_amdgcn_mfma_f32_32x32x16_bf16((sl == 0) ? fA : fB,
                                                          *(const bf16x8*)fr, oaccA, 0, 0, 0);
        else
          oaccB = __builtin_amdgcn_mfma_f32_32x32x16_bf16((sl == 0) ? fA : fB,
                                                          *(const bf16x8*)fr, oaccB, 0, 0, 0);
      }
    }
    const f32x16 oacc = oaccA + oaccB;

    // epilogue: regs0-3 = d 0-3 (hw=0) / d 4-7 (hw=1); reg4 = rowsum (both halves)
    const int scol = s & 127, srow = s >> 7;
    const float inv = __builtin_amdgcn_rcpf(oacc[4]);
    const uint32_t o01 = pk_bf16(oacc[0] * inv, oacc[1] * inv);
    const uint32_t o23 = pk_bf16(oacc[2] * inv, oacc[3] * inv);
    const int h = hi * 32 + l31;
    const size_t row = (size_t)(b * 2048 + h * 16 + srow);
    *(uint2*)(outr + row * E_ + scol * 8 + hw * 4) = make_uint2(o01, o23);
  }
}

// ---------------- W (f32) -> bf16 ----------------
__global__ __launch_bounds__(256) void wconv(const float* __restrict__ W,
                                             ushort* __restrict__ Wb) {
  const int i = blockIdx.x * 256 + threadIdx.x;
  const float4 v = ((const float4*)W)[i];
  ushort4 o;
  o.x = f2bf(v.x); o.y = f2bf(v.y); o.z = f2bf(v.z); o.w = f2bf(v.w);
  ((ushort4*)Wb)[i] = o;
}

// ---------------- Stage 2: C[m,n] = sum_k A[m,k]*W[n,k] + bias[n] ----------------
// Double-buffered 2-phase: stage(k+1) issued BEFORE ds_read/MFMA of k, one
// barrier per iteration (__syncthreads drains vmcnt -> staged tile ready).
__global__ __launch_bounds__(256) void gemm_bt(const ushort* __restrict__ A,
                                               const ushort* __restrict__ Bw,
                                               const float* __restrict__ bias,
                                               float* __restrict__ C) {
  __shared__ __align__(16) ushort As[2][128 * 32];   // 2 x 8 KB
  __shared__ __align__(16) ushort Bs[2][128 * 32];

  const int t = threadIdx.x;
  const int lane = t & 63;
  const int wavei = t >> 6;
  const int wr = wavei >> 1, wc = wavei & 1;
  const int lhi = lane >> 4, llo = lane & 15;
  const size_t ar0 = (size_t)blockIdx.x * 128;
  const size_t br0 = (size_t)blockIdx.y * 128;

  const int c0 = t, c1 = t + 256;
  const int r0 = c0 >> 2, kp0 = (c0 & 3) * 8;
  const int r1 = c1 >> 2, kp1 = (c1 & 3) * 8;

  auto stage = [&](int buf, int k0) {
    __builtin_amdgcn_global_load_lds((const glb_t*)(A  + (ar0 + r0) * E_ + k0 + kp0),
                                     (lds_t*)(As[buf] + c0 * 8), 16, 0, 0);
    __builtin_amdgcn_global_load_lds((const glb_t*)(A  + (ar0 + r1) * E_ + k0 + kp1),
                                     (lds_t*)(As[buf] + c1 * 8), 16, 0, 0);
    __builtin_amdgcn_global_load_lds((const glb_t*)(Bw + (br0 + r0) * E_ + k0 + kp0),
                                     (lds_t*)(Bs[buf] + c0 * 8), 16, 0, 0);
    __builtin_amdgcn_global_load_lds((const glb_t*)(Bw + (br0 + r1) * E_ + k0 + kp1),
                                     (lds_t*)(Bs[buf] + c1 * 8), 16, 0, 0);
  };

  f32x4 acc[4][4] = {};

  stage(0, 0);
  __syncthreads();                       // drains vmcnt: buf0 ready

  for (int k0 = 0; k0 < E_; k0 += 32) {
    const int cur = (k0 >> 5) & 1;
    if (k0 + 32 < E_) stage(cur ^ 1, k0 + 32);   // overlap with MFMA below

    bf16x8 af[4], bfr[4];
    #pragma unroll
    for (int i = 0; i < 4; ++i)
      af[i] = *(const bf16x8*)(As[cur] + (wr * 64 + i * 16 + llo) * 32 + lhi * 8);
    #pragma unroll
    for (int j = 0; j < 4; ++j)
      bfr[j] = *(const bf16x8*)(Bs[cur] + (wc * 64 + j * 16 + llo) * 32 + lhi * 8);

    #pragma unroll
    for (int i = 0; i < 4; ++i)
      #pragma unroll
      for (int j = 0; j < 4; ++j)
        acc[i][j] = __builtin_amdgcn_mfma_f32_16x16x32_bf16(af[i], bfr[j], acc[i][j], 0, 0, 0);

    __syncthreads();                     // reads of cur done + staged loads landed
  }

  #pragma unroll
  for (int j = 0; j < 4; ++j) {
    const int n = (int)br0 + wc * 64 + j * 16 + llo;
    const float bj = bias[n];
    #pragma unroll
    for (int i = 0; i < 4; ++i) {
      const int mb = (int)ar0 + wr * 64 + i * 16 + lhi * 4;
      #pragma unroll
      for (int r = 0; r < 4; ++r) {
        C[(size_t)(mb + r) * E_ + n] = acc[i][j][r] + bj;
      }
    }
  }
}

extern "C" void kernel_launch(void* const* d_in, const int* in_sizes, int n_in,
                              void* d_out, int out_size, void* d_ws, size_t ws_size,
                              hipStream_t stream) {
  const float* x     = (const float*)d_in[0];
  const float* theta = (const float*)d_in[1];
  const float* W     = (const float*)d_in[2];
  const float* bias  = (const float*)d_in[3];
  float* out = (float*)d_out;

  ushort* outr = (ushort*)d_ws;
  ushort* Wb   = (ushort*)((char*)d_ws + (size_t)M_ * E_ * 2);

  qattn<<<M_ / PPB, 256, 0, stream>>>(x, theta, outr);
  wconv<<<(E_ * E_) / (256 * 4), 256, 0, stream>>>(W, Wb);
  dim3 g(M_ / 128, E_ / 128);
  gemm_bt<<<g, 256, 0, stream>>>(outr, Wb, bias, out);
}